// Round 2
// baseline (4031.955 us; speedup 1.0000x reference)
//
#include <hip/hip_runtime.h>
#include <stdint.h>

#define T_  64
#define A_  256
#define GG_ 16
#define H_  128

// ---- workspace layout (float offsets) ----
#define OFF_WS    0          // W_s transposed soc_W: [128][1024]
#define OFF_WCATT 131072     // WcatT: [256][512]
#define OFF_BSUM  262144     // [512]
#define OFF_S     262656     // S: [256][1024]
#define OFF_X     524800     // X: [256][256]
#define OFF_GATES 590336     // gates: [256][512]
#define OFF_H0    721408     // h ping-pong buf 0: [256][128]
#define OFF_H1    754176
#define OFF_C0    786944
#define OFF_C1    819712
#define OFF_FLAG  852480     // int flag (mask encoding mode)
#define IDX_OFF_BYTES 3410048ULL   // uint8 sparse indices start (16B aligned)

__device__ __forceinline__ float sigf(float x){ return 1.0f/(1.0f+__expf(-x)); }
__device__ __forceinline__ float tanhfast(float x){ float e = __expf(2.0f*x); return 1.0f - 2.0f/(e+1.0f); }

__device__ __forceinline__ bool maskAt(const void* m, int mode, int i){
  if (mode == 0) return ((const int*)m)[i] != 0;
  if (mode == 2) return ((const float*)m)[i] != 0.0f;
  return ((const unsigned char*)m)[i] != 0;
}

// ---- detect mask encoding: 0=int32, 1=uint8/bool, 2=float32 ----
__global__ void k_maskmode(const unsigned* m, int* flag){
  __shared__ int r_int[256]; __shared__ int r_flt[256];
  int ok_int = 1, ok_flt = 1;
  for (int i = threadIdx.x; i < 4096; i += 256){
    unsigned v = m[i];
    if (v > 1u) ok_int = 0;
    if (v != 0u && v != 0x3F800000u) ok_flt = 0;
  }
  r_int[threadIdx.x]=ok_int; r_flt[threadIdx.x]=ok_flt; __syncthreads();
  for (int s=128;s>0;s>>=1){
    if (threadIdx.x<s){ r_int[threadIdx.x]&=r_int[threadIdx.x+s]; r_flt[threadIdx.x]&=r_flt[threadIdx.x+s]; }
    __syncthreads();
  }
  if (threadIdx.x==0) *flag = r_int[0] ? 0 : (r_flt[0] ? 2 : 1);
}

// ---- init: weight transposes, bias sum, state copy ----
__global__ void k_init(const float* __restrict__ soc_W, const float* __restrict__ W_ih,
                       const float* __restrict__ W_hh, const float* __restrict__ b_ih,
                       const float* __restrict__ b_hh, const float* __restrict__ h0,
                       const float* __restrict__ c0, float* __restrict__ ws){
  const int n = 131072+131072+512+32768;
  for (int id = blockIdx.x*blockDim.x + threadIdx.x; id < n; id += gridDim.x*blockDim.x){
    if (id < 131072){
      int hh = id >> 10, j = id & 1023, g = j >> 6, e = j & 63;
      ws[OFF_WS + id] = soc_W[e*2048 + g*128 + hh];
    } else if (id < 262144){
      int id2 = id - 131072; int col = id2 >> 9, q = id2 & 511;
      ws[OFF_WCATT + id2] = (col < 128) ? W_ih[q*128+col] : W_hh[q*128+col-128];
    } else if (id < 262656){
      int q = id - 262144; ws[OFF_BSUM + q] = b_ih[q] + b_hh[q];
    } else {
      int i = id - 262656;
      ws[OFF_H1 + i] = h0[i];
      ws[OFF_C1 + i] = c0[i];
    }
  }
}

// ---- sparse-encode grid: per (t,a,g) row of 256, compact nonzero k (uint8) ----
__global__ void k_encode(const float* __restrict__ grid, unsigned char* __restrict__ idx,
                         unsigned char* __restrict__ cnt, int CAP){
  int wave = threadIdx.x >> 6, lane = threadIdx.x & 63;
  long long row = (long long)blockIdx.x*4 + wave;   // < 262144
  const float4 v = *(const float4*)(grid + row*256 + lane*4);
  unsigned long long lt = (lane == 0) ? 0ULL : ((1ULL << lane) - 1ULL);
  int base = 0;
  #pragma unroll
  for (int i=0;i<4;i++){
    float x = (i==0)?v.x:(i==1)?v.y:(i==2)?v.z:v.w;
    bool nz = (x != 0.0f);
    unsigned long long m = __ballot(nz);
    int pos = base + __popcll(m & lt);
    if (nz && pos < CAP) idx[(size_t)row*CAP + pos] = (unsigned char)(lane*4+i);
    base += __popcll(m);
  }
  if (lane==0) cnt[row] = (unsigned char)(base < CAP ? base : CAP);
}

// ---- per step: fused pointwise(t-1) + S(t) = (m_t .* h) @ W_s ----
// grid 128 = 8 kb (32 agents) x 16 jb (64 j); block 256
__global__ void k_step_sp(int t, const float* __restrict__ h0, const float* __restrict__ c0,
                          const void* __restrict__ mask, const float* __restrict__ out_W,
                          const float* __restrict__ out_b, float* __restrict__ ws,
                          float* __restrict__ d_out){
  const int mode = *(const int*)(ws + OFF_FLAG);
  int kb = blockIdx.x >> 4, jb = blockIdx.x & 15;
  __shared__ float lds_h[32][128];
  __shared__ float lds_hn[32][128];
  const float* gates = ws + OFF_GATES;
  const float* hb_old = ws + ((t & 1) ? OFF_H1 : OFF_H0);
  const float* cb_old = ws + ((t & 1) ? OFF_C1 : OFF_C0);
  float* hb_new = ws + (((t-1) & 1) ? OFF_H1 : OFF_H0);
  float* cb_new = ws + (((t-1) & 1) ? OFF_C1 : OFF_C0);

  if (t == 0){
    for (int item = threadIdx.x; item < 4096; item += 256){
      int kl = item >> 7, hh = item & 127, k = kb*32 + kl;
      float hv = h0[k*128 + hh];
      lds_h[kl][hh] = maskAt(mask, mode, k) ? hv : 0.0f;
    }
  } else {
    for (int item = threadIdx.x; item < 4096; item += 256){
      int kl = item >> 7, hh = item & 127, k = kb*32 + kl;
      float gi = gates[k*512 + hh];
      float gf = gates[k*512 + 128 + hh];
      float gg = gates[k*512 + 256 + hh];
      float go = gates[k*512 + 384 + hh];
      float c_old = cb_old[k*128+hh];
      float h_old = hb_old[k*128+hh];
      float iv = sigf(gi), fv = sigf(gf), gv = tanhfast(gg), ov = sigf(go);
      float c_new = fv*c_old + iv*gv;
      float h_new = ov*tanhfast(c_new);
      bool mprev = maskAt(mask, mode, (t-1)*A_ + k);
      float h_cur = mprev ? h_new : h_old;
      float c_cur = mprev ? c_new : c_old;
      lds_h[kl][hh] = maskAt(mask, mode, t*A_ + k) ? h_cur : 0.0f;
      if (jb == 0){
        lds_hn[kl][hh] = h_new;
        hb_new[k*128+hh] = h_cur;
        cb_new[k*128+hh] = c_cur;
      }
    }
  }
  __syncthreads();

  if (t > 0 && jb == 0 && threadIdx.x < 64){
    int kl = threadIdx.x >> 1, r = threadIdx.x & 1, k = kb*32 + kl;
    float s = out_b[r];
    for (int ii=0; ii<128; ii++){
      int hh = (ii + kl*4) & 127;   // rotate to avoid LDS bank conflicts
      s += lds_hn[kl][hh]*out_W[r*128+hh];
    }
    d_out[(t-1)*512 + k*2 + r] = maskAt(mask, mode, (t-1)*A_ + k) ? s : 0.0f;
  }

  // S phase: S[k][j] = sum_hh lds_h[k][hh] * W_s[hh][j]
  int j = jb*64 + (threadIdx.x & 63);
  int slot = threadIdx.x >> 6;           // 4 slots x 8 agents
  float acc[8];
  #pragma unroll
  for (int kk=0; kk<8; kk++) acc[kk] = 0.0f;
  const float* Wsp = ws + OFF_WS;
  for (int hh=0; hh<128; hh++){
    float w = Wsp[hh*1024 + j];
    #pragma unroll
    for (int kk=0; kk<8; kk++) acc[kk] += lds_h[slot*8+kk][hh]*w;
  }
  float* Sp = ws + OFF_S;
  #pragma unroll
  for (int kk=0; kk<8; kk++) Sp[(kb*32 + slot*8 + kk)*1024 + j] = acc[kk];
}

// ---- per step: sparse gather soc + pos, build X = [pos|soc|h] ----
// grid 256 (agent), block 256 (4 slots x 64 e)
__global__ void k_socx(int t, const float* __restrict__ input, const float* __restrict__ pos_W,
                       const float* __restrict__ pos_b, const float* __restrict__ soc_b,
                       float* __restrict__ ws, const unsigned char* __restrict__ idx,
                       const unsigned char* __restrict__ cnt, int CAP){
  int a = blockIdx.x, e = threadIdx.x & 63, slot = threadIdx.x >> 6;
  const float* Sp = ws + OFF_S;
  __shared__ float red[4][64];
  float acc = 0.0f;
  for (int g = slot*4; g < slot*4+4; g++){
    int row = (t*A_ + a)*GG_ + g;
    int c = cnt[row];
    const uint4* bp4 = (const uint4*)(idx + (size_t)row*CAP);
    for (int wq = 0; wq*16 < c; wq++){
      uint4 u = bp4[wq];
      int rem = c - wq*16; if (rem > 16) rem = 16;
      #pragma unroll
      for (int d=0; d<4; d++){
        unsigned uw = (d==0)?u.x:(d==1)?u.y:(d==2)?u.z:u.w;
        #pragma unroll
        for (int b=0; b<4; b++){
          int ii = d*4+b;
          if (ii < rem){
            int k = (uw >> (b*8)) & 255;
            acc += Sp[k*1024 + g*64 + e];
          }
        }
      }
    }
  }
  red[slot][e] = acc; __syncthreads();
  if (slot == 0){
    float tot = red[0][e]+red[1][e]+red[2][e]+red[3][e];
    float soc = fmaxf(tot + soc_b[e], 0.0f);
    float x0 = input[t*512 + a*2], x1 = input[t*512 + a*2 + 1];
    float p = fmaxf(x0*pos_W[e*2] + x1*pos_W[e*2+1] + pos_b[e], 0.0f);
    const float* hbp = ws + (((t-1) & 1) ? OFF_H1 : OFF_H0);  // state after t-1
    float* X = ws + OFF_X + a*256;
    X[e] = p; X[64+e] = soc;
    X[128+e] = hbp[a*128+e]; X[192+e] = hbp[a*128+64+e];
  }
}

// ---- per step: gates = X @ WcatT + bsum ----
// grid 128 = 16 ab (16 agents) x 8 qb (64 gates); block 256
__global__ void k_gatesk(float* __restrict__ ws){
  int ab = blockIdx.x >> 3, qb = blockIdx.x & 7;
  __shared__ float ldsX[16][256];
  const float* X = ws + OFF_X;
  for (int item = threadIdx.x; item < 4096; item += 256){
    int al = item >> 8, col = item & 255;
    ldsX[al][col] = X[(ab*16+al)*256 + col];
  }
  __syncthreads();
  int q = qb*64 + (threadIdx.x & 63);
  int slot = threadIdx.x >> 6;     // 4 slots x 4 agents
  float acc0=0.f,acc1=0.f,acc2=0.f,acc3=0.f;
  const float* Wt = ws + OFF_WCATT;
  for (int col=0; col<256; col++){
    float w = Wt[col*512 + q];
    acc0 += ldsX[slot*4+0][col]*w;
    acc1 += ldsX[slot*4+1][col]*w;
    acc2 += ldsX[slot*4+2][col]*w;
    acc3 += ldsX[slot*4+3][col]*w;
  }
  float b = ws[OFF_BSUM + q];
  float* G = ws + OFF_GATES;
  G[(ab*16+slot*4+0)*512 + q] = acc0 + b;
  G[(ab*16+slot*4+1)*512 + q] = acc1 + b;
  G[(ab*16+slot*4+2)*512 + q] = acc2 + b;
  G[(ab*16+slot*4+3)*512 + q] = acc3 + b;
}

// ---- final: pointwise for t=63, write outs row 63 + final h,c ----
__global__ void k_final(const void* __restrict__ mask, const float* __restrict__ out_W,
                        const float* __restrict__ out_b, float* __restrict__ ws,
                        float* __restrict__ d_out){
  const int mode = *(const int*)(ws + OFF_FLAG);
  int kb = blockIdx.x;   // 8 blocks x 32 agents
  __shared__ float lds_hn[32][128];
  const float* gates = ws + OFF_GATES;
  const float* hb_old = ws + OFF_H0;   // state after step 62 lives in buf0
  const float* cb_old = ws + OFF_C0;
  for (int item = threadIdx.x; item < 4096; item += 256){
    int kl = item >> 7, hh = item & 127, k = kb*32 + kl;
    float gi = gates[k*512 + hh];
    float gf = gates[k*512 + 128 + hh];
    float gg = gates[k*512 + 256 + hh];
    float go = gates[k*512 + 384 + hh];
    float c_old = cb_old[k*128+hh];
    float h_old = hb_old[k*128+hh];
    float iv = sigf(gi), fv = sigf(gf), gv = tanhfast(gg), ov = sigf(go);
    float c_new = fv*c_old + iv*gv;
    float h_new = ov*tanhfast(c_new);
    bool mprev = maskAt(mask, mode, 63*A_ + k);
    float h_cur = mprev ? h_new : h_old;
    float c_cur = mprev ? c_new : c_old;
    lds_hn[kl][hh] = h_new;
    d_out[32768 + k*128 + hh] = h_cur;
    d_out[65536 + k*128 + hh] = c_cur;
  }
  __syncthreads();
  if (threadIdx.x < 64){
    int kl = threadIdx.x >> 1, r = threadIdx.x & 1, k = kb*32 + kl;
    float s = out_b[r];
    for (int ii=0; ii<128; ii++){
      int hh = (ii + kl*4) & 127;
      s += lds_hn[kl][hh]*out_W[r*128+hh];
    }
    d_out[63*512 + k*2 + r] = maskAt(mask, mode, 63*A_ + k) ? s : 0.0f;
  }
}

extern "C" void kernel_launch(void* const* d_in, const int* in_sizes, int n_in,
                              void* d_out, int out_size, void* d_ws, size_t ws_size,
                              hipStream_t stream) {
  const float* input = (const float*)d_in[0];
  const float* grid  = (const float*)d_in[1];
  const float* h0    = (const float*)d_in[2];
  const float* c0    = (const float*)d_in[3];
  const void*  mask  = d_in[4];
  const float* pos_W = (const float*)d_in[5];
  const float* pos_b = (const float*)d_in[6];
  const float* soc_W = (const float*)d_in[7];
  const float* soc_b = (const float*)d_in[8];
  const float* W_ih  = (const float*)d_in[9];
  const float* W_hh  = (const float*)d_in[10];
  const float* b_ih  = (const float*)d_in[11];
  const float* b_hh  = (const float*)d_in[12];
  const float* out_W = (const float*)d_in[13];
  const float* out_b = (const float*)d_in[14];
  float* ws  = (float*)d_ws;
  float* out = (float*)d_out;

  const size_t NROWS = (size_t)T_*A_*GG_;   // 262144
  int CAP = 48;
  if (IDX_OFF_BYTES + NROWS*(size_t)CAP + NROWS > ws_size) CAP = 32;
  if (IDX_OFF_BYTES + NROWS*(size_t)CAP + NROWS > ws_size) CAP = 16;
  unsigned char* idx = (unsigned char*)d_ws + IDX_OFF_BYTES;
  unsigned char* cnt = idx + NROWS*(size_t)CAP;

  k_maskmode<<<1, 256, 0, stream>>>((const unsigned*)mask, (int*)(ws + OFF_FLAG));
  k_init<<<1154, 256, 0, stream>>>(soc_W, W_ih, W_hh, b_ih, b_hh, h0, c0, ws);
  k_encode<<<65536, 256, 0, stream>>>(grid, idx, cnt, CAP);

  for (int t = 0; t < T_; t++){
    k_step_sp<<<128, 256, 0, stream>>>(t, h0, c0, mask, out_W, out_b, ws, out);
    k_socx<<<256, 256, 0, stream>>>(t, input, pos_W, pos_b, soc_b, ws, idx, cnt, CAP);
    k_gatesk<<<128, 256, 0, stream>>>(ws);
  }
  k_final<<<8, 256, 0, stream>>>(mask, out_W, out_b, ws, out);
}